// Round 5
// baseline (1153.005 us; speedup 1.0000x reference)
//
#include <hip/hip_runtime.h>

#define NQ 4096
#define NPT 1024
#define CAP 16

typedef float vf2 __attribute__((ext_vector_type(2)));

struct KnnSm { float4 pts[2048]; unsigned long long qbuf[CAP * 256]; };   // 64 KB
struct FpsSm { float pz[NQ]; float4 red[2][4]; };                          // 16.1 KB
struct GemmSm {
  float fnb[16][132]; float fqb[16][8]; float Alds[128][8]; float Dlds[128][8];
  int last;
};
union FusedSm { KnnSm k; FpsSm f; GemmSm g; };

struct Ctl { int f8_done, knn_done, fps_done, stats_done, fin_done, pad0, pad1, pad2;
             int fps_prog[8]; };   // zeroed by memset each launch

// lexicographic max of (hi,lo) with (cx,cy) payload across wave via DPP;
// result lands in lane 63. bound_ctrl=true: invalid lanes read 0 for all
// fields; key (0,0) always loses to any real key (lo = 4095-idx+1 > 0...
// actually lo >= 0, but hi=dist>=0 and real lo>0 only if idx<4095; ties at
// (0,0) would pick zero coords only if ALL keys are (0,0) - impossible since
// every lane contributes a real candidate with lo = 4095-idx >= 0 and
// distinct idx => at most one real key equals (0,0) and it wins correctly
// because tk requires strict >.
#define DPP_STEP4(CTRL)                                                         \
  {                                                                             \
    unsigned sh = (unsigned)__builtin_amdgcn_update_dpp(0, (int)hi, CTRL, 0xF, 0xF, true); \
    unsigned sl = (unsigned)__builtin_amdgcn_update_dpp(0, (int)lo, CTRL, 0xF, 0xF, true); \
    unsigned sx = (unsigned)__builtin_amdgcn_update_dpp(0, (int)__float_as_uint(cx), CTRL, 0xF, 0xF, true); \
    unsigned sy = (unsigned)__builtin_amdgcn_update_dpp(0, (int)__float_as_uint(cy), CTRL, 0xF, 0xF, true); \
    bool tk = (sh > hi) || ((sh == hi) && (sl > lo));                           \
    hi = tk ? sh : hi;                                                          \
    lo = tk ? sl : lo;                                                          \
    cx = tk ? __uint_as_float(sx) : cx;                                         \
    cy = tk ? __uint_as_float(sy) : cy;                                         \
  }

__device__ inline void spin_ge(int* p, int target) {
  while (__hip_atomic_load(p, __ATOMIC_RELAXED, __HIP_MEMORY_SCOPE_AGENT) < target)
    __builtin_amdgcn_s_sleep(32);
}
__device__ inline void release_inc(int* p) {
  __threadfence();
  __hip_atomic_fetch_add(p, 1, __ATOMIC_RELAXED, __HIP_MEMORY_SCOPE_AGENT);
}

__global__ __launch_bounds__(256) void mega_kernel(
    const float* __restrict__ x, const float* __restrict__ f,
    const float* __restrict__ w_in, const float* __restrict__ b_in,
    const float* __restrict__ w1, const float* __restrict__ gnw,
    const float* __restrict__ gnb, float* __restrict__ f8t,
    int* __restrict__ knn, int* __restrict__ fps_g, double* __restrict__ stats,
    float* __restrict__ musd, Ctl* __restrict__ ctl, float* __restrict__ out) {
  __shared__ FusedSm sm;
  int tid = threadIdx.x;
  int bk = blockIdx.x;

  if (bk < 8) {
    // ===== FPS: coords carried through reduce; 2 LDS windows per iter =======
#pragma clang fp contract(off)
    int b = bk;
    const float* xb = x + (size_t)b * 3 * NQ;
    vf2 px2[8], py2[8], pz2[8], d2[8];
#pragma unroll
    for (int p = 0; p < 8; p++) {
      int i0 = (p << 9) + tid, i1 = i0 + 256;   // slot 2p -> i0, slot 2p+1 -> i1
      float X0 = xb[i0], Y0 = xb[NQ + i0], Z0 = xb[2 * NQ + i0];
      float X1 = xb[i1], Y1 = xb[NQ + i1], Z1 = xb[2 * NQ + i1];
      px2[p] = vf2{X0, X1}; py2[p] = vf2{Y0, Y1}; pz2[p] = vf2{Z0, Z1};
      sm.f.pz[i0] = Z0; sm.f.pz[i1] = Z1;
    }
    float x0 = xb[0], y0 = xb[NQ], z0 = xb[2 * NQ];
    {
      vf2 wxv = vf2{x0, x0}, wyv = vf2{y0, y0}, wzv = vf2{z0, z0};
#pragma unroll
      for (int p = 0; p < 8; p++) {
        vf2 dx = px2[p] - wxv, dy = py2[p] - wyv, dz = pz2[p] - wzv;
        vf2 a = dx * dx, bq = dy * dy, cq = dz * dz;
        d2[p] = (a + bq) + cq;                    // ((a+b)+c), no fma
      }
    }
    if (tid == 0) fps_g[b * NPT] = 0;
    __syncthreads();
    for (int it = 1; it < NPT; it++) {
      // tree argmax over 16 slots carrying (val, slot, x, y);
      // strict > keeps lower slot = lower global idx (np.argmax tie-break)
      float tv[8], tx[8], ty[8]; int ts[8];
#pragma unroll
      for (int s = 0; s < 8; s++) {
        bool g = d2[s].y > d2[s].x;
        tv[s] = g ? d2[s].y : d2[s].x;
        ts[s] = g ? (2 * s + 1) : (2 * s);
        tx[s] = g ? px2[s].y : px2[s].x;
        ty[s] = g ? py2[s].y : py2[s].x;
      }
#pragma unroll
      for (int s = 0; s < 4; s++) {
        bool g = tv[2 * s + 1] > tv[2 * s];
        tv[s] = g ? tv[2 * s + 1] : tv[2 * s];
        ts[s] = g ? ts[2 * s + 1] : ts[2 * s];
        tx[s] = g ? tx[2 * s + 1] : tx[2 * s];
        ty[s] = g ? ty[2 * s + 1] : ty[2 * s];
      }
#pragma unroll
      for (int s = 0; s < 2; s++) {
        bool g = tv[2 * s + 1] > tv[2 * s];
        tv[s] = g ? tv[2 * s + 1] : tv[2 * s];
        ts[s] = g ? ts[2 * s + 1] : ts[2 * s];
        tx[s] = g ? tx[2 * s + 1] : tx[2 * s];
        ty[s] = g ? ty[2 * s + 1] : ty[2 * s];
      }
      bool gf = tv[1] > tv[0];
      float mv = gf ? tv[1] : tv[0];
      int ms = gf ? ts[1] : ts[0];
      float cx = gf ? tx[1] : tx[0];
      float cy = gf ? ty[1] : ty[0];
      unsigned hi = __float_as_uint(mv);          // dist>=0: bits uint-monotone
      unsigned lo = 4095u - (unsigned)((ms << 8) + tid);  // max => lowest idx
      DPP_STEP4(0x111)  // row_shr:1
      DPP_STEP4(0x112)  // row_shr:2
      DPP_STEP4(0x114)  // row_shr:4
      DPP_STEP4(0x118)  // row_shr:8
      DPP_STEP4(0x142)  // row_bcast:15
      DPP_STEP4(0x143)  // row_bcast:31  -> lane 63 holds wave max
      int buf = it & 1;
      if ((tid & 63) == 63)
        sm.f.red[buf][tid >> 6] =
            make_float4(__uint_as_float(hi), __uint_as_float(lo), cx, cy);
      __syncthreads();  // single barrier; parity double-buffer kills WAR
      float4 r0 = sm.f.red[buf][0], r1 = sm.f.red[buf][1];
      float4 r2 = sm.f.red[buf][2], r3 = sm.f.red[buf][3];
      // 4-way select on (hi,lo) keys, payload follows
      {
        unsigned h0 = __float_as_uint(r0.x), l0 = __float_as_uint(r0.y);
        unsigned h1 = __float_as_uint(r1.x), l1 = __float_as_uint(r1.y);
        unsigned h2 = __float_as_uint(r2.x), l2 = __float_as_uint(r2.y);
        unsigned h3 = __float_as_uint(r3.x), l3 = __float_as_uint(r3.y);
        bool t1 = (h1 > h0) || ((h1 == h0) && (l1 > l0));
        unsigned ha = t1 ? h1 : h0, la = t1 ? l1 : l0;
        float xa = t1 ? r1.z : r0.z, ya = t1 ? r1.w : r0.w;
        bool t3 = (h3 > h2) || ((h3 == h2) && (l3 > l2));
        unsigned hb = t3 ? h3 : h2, lb = t3 ? l3 : l2;
        float xbw = t3 ? r3.z : r2.z, yb = t3 ? r3.w : r2.w;
        bool tb = (hb > ha) || ((hb == ha) && (lb > la));
        la = tb ? lb : la;
        r0.z = tb ? xbw : xa;
        r0.w = tb ? yb : ya;
        r0.y = __uint_as_float(la);
      }
      int wi = 4095 - (int)__float_as_uint(r0.y);
      float wx = r0.z, wy = r0.w;
      float wz = sm.f.pz[wi];                     // issued early; overlaps below
      if (tid == 0) {
        fps_g[b * NPT + it] = wi;
        if (((it + 1) & 31) == 0) {               // publish prefix progress
          __threadfence();
          __hip_atomic_store(&ctl->fps_prog[b], it, __ATOMIC_RELAXED,
                             __HIP_MEMORY_SCOPE_AGENT);
        }
      }
      vf2 wxv = vf2{wx, wx}, wyv = vf2{wy, wy};
      vf2 sxy[8];
#pragma unroll
      for (int p = 0; p < 8; p++) {               // z-independent part first
        vf2 dx = px2[p] - wxv, dy = py2[p] - wyv;
        vf2 a = dx * dx, bq = dy * dy;
        sxy[p] = a + bq;
      }
      vf2 wzv = vf2{wz, wz};
#pragma unroll
      for (int p = 0; p < 8; p++) {
        vf2 dz = pz2[p] - wzv;
        vf2 cq = dz * dz;
        vf2 d = sxy[p] + cq;                      // ((a+b)+c) preserved
        d2[p].x = fminf(d2[p].x, d.x);
        d2[p].y = fminf(d2[p].y, d.y);
      }
    }
  } else if (bk < 136) {
    // ================= kNN, lazy-queue top-16 (transposed queue) =============
#pragma clang fp contract(off)
    int rel = bk - 8;
    int b = rel >> 4;
    int n0 = (rel & 15) << 8;
    const float* xb = x + (size_t)b * 3 * NQ;
    int n = n0 + tid;
    float qx = xb[n], qy = xb[NQ + n], qz = xb[2 * NQ + n];
    float qw = (qx * qx + qy * qy) + qz * qz;
    float bd[16]; int bi[16];
#pragma unroll
    for (int i = 0; i < 16; i++) { bd[i] = 3.4e38f; bi[i] = -1; }
    float thr = 3.4e38f;
    int cnt = 0;

    auto insert16 = [&](float ed, int em) {
#pragma unroll
      for (int i2 = 15; i2 >= 1; --i2) {
        bool ltp = ed < bd[i2 - 1];
        bool ltc = ed < bd[i2];
        float nv = ltp ? bd[i2 - 1] : ed;
        int ni = ltp ? bi[i2 - 1] : em;
        bd[i2] = ltc ? nv : bd[i2];
        bi[i2] = ltc ? ni : bi[i2];
      }
      bool lt0 = ed < bd[0];
      bd[0] = lt0 ? ed : bd[0];
      bi[0] = lt0 ? em : bi[0];
    };
    auto drain = [&]() {
#pragma unroll 1
      for (int j = 0; j < cnt; j++) {
        unsigned long long e = sm.k.qbuf[j * 256 + tid];
        float ed = __uint_as_float((unsigned int)(e >> 32));
        int em = (int)(e & 0xFFFFFFFFull);
        if (ed < bd[15]) insert16(ed, em);
      }
      cnt = 0;
      thr = bd[15];
    };

    for (int c0 = 0; c0 < NQ; c0 += 2048) {
      __syncthreads();
      for (int i = tid; i < 2048; i += 256) {
        int g = c0 + i;
        float pxv = xb[g], pyv = xb[NQ + g], pzv = xb[2 * NQ + g];
        float sq = (pxv * pxv + pyv * pyv) + pzv * pzv;
        sm.k.pts[i] = make_float4(pxv, pyv, pzv, sq);
      }
      __syncthreads();
      for (int m0 = 0; m0 < 2048; m0 += 8) {
        float4 p[8];
#pragma unroll
        for (int j = 0; j < 8; j++) p[j] = sm.k.pts[m0 + j];
        float d[8];
#pragma unroll
        for (int j = 0; j < 8; j++) {
          float dot = (qx * p[j].x + qy * p[j].y) + qz * p[j].z;
          d[j] = (qw + p[j].w) - 2.0f * dot;
        }
#pragma unroll
        for (int j = 0; j < 8; j++) {
          if (d[j] < thr) {
            sm.k.qbuf[cnt * 256 + tid] =
                ((unsigned long long)__float_as_uint(d[j]) << 32) |
                (unsigned int)(c0 + m0 + j);
            cnt++;
          }
        }
        if (__ballot(cnt > CAP - 8)) drain();
      }
    }
    drain();

    int4* dst = (int4*)(knn + (((size_t)(b << 12) + n) << 4));
    dst[0] = make_int4(bi[0], bi[1], bi[2], bi[3]);
    dst[1] = make_int4(bi[4], bi[5], bi[6], bi[7]);
    dst[2] = make_int4(bi[8], bi[9], bi[10], bi[11]);
    dst[3] = make_int4(bi[12], bi[13], bi[14], bi[15]);
    __syncthreads();
    if (tid == 0) release_inc(&ctl->knn_done);
  } else if (bk < 264) {
    // ================= f8 (1x1 conv) ========================================
    int rel = bk - 136;
    int t = rel * 256 + tid;
    int b = t >> 12, n = t & 4095;
    const float* fb = f + (size_t)b * 3 * NQ + n;
    float f0 = fb[0], f1 = fb[NQ], f2 = fb[2 * NQ];
    float o8v[8];
#pragma unroll
    for (int o = 0; o < 8; o++) {
      o8v[o] = w_in[o * 3 + 0] * f0 + w_in[o * 3 + 1] * f1 + w_in[o * 3 + 2] * f2 + b_in[o];
    }
    float4* dst = (float4*)(f8t + ((size_t)t << 3));
    dst[0] = make_float4(o8v[0], o8v[1], o8v[2], o8v[3]);
    dst[1] = make_float4(o8v[4], o8v[5], o8v[6], o8v[7]);
    __syncthreads();
    if (tid == 0) release_inc(&ctl->f8_done);
  } else if (bk < 2312) {
    // ================= stats (+ inline finalize in last block) ==============
    if (tid == 0) { spin_ge(&ctl->knn_done, 128); spin_ge(&ctl->f8_done, 128); }
    __syncthreads();
    __threadfence();
    int rel = bk - 264;
    int b = rel >> 8;
    int n0 = (rel & 255) << 4;
    if (tid < 128) {
#pragma unroll
      for (int c = 0; c < 8; c++) {
        float a = w1[tid * 16 + c];
        sm.g.Alds[tid][c] = a;
        sm.g.Dlds[tid][c] = w1[tid * 16 + 8 + c] - a;
      }
    }
    int nl = tid & 15, kk = tid >> 4;
    int nmy = n0 + nl;
    int idx = knn[(((size_t)(b << 12) + nmy) << 4) + kk];
    const float4* fp4 = (const float4*)(f8t + (((size_t)(b << 12) + idx) << 3));
    float4 v0 = fp4[0], v1 = fp4[1];
    float* dstp = &sm.g.fnb[nl][kk << 3];
    ((float4*)dstp)[0] = v0;
    ((float4*)dstp)[1] = v1;
    if (tid < 16) {
      const float4* fq4 = (const float4*)(f8t + (((size_t)(b << 12) + n0 + tid) << 3));
      float4 a = fq4[0], c4 = fq4[1];
      sm.g.fqb[tid][0] = a.x; sm.g.fqb[tid][1] = a.y; sm.g.fqb[tid][2] = a.z; sm.g.fqb[tid][3] = a.w;
      sm.g.fqb[tid][4] = c4.x; sm.g.fqb[tid][5] = c4.y; sm.g.fqb[tid][6] = c4.z; sm.g.fqb[tid][7] = c4.w;
    }
    __syncthreads();
    int o8 = tid >> 4;
    int obase = o8 << 3;
    float fq[8];
#pragma unroll
    for (int c = 0; c < 8; c++) fq[c] = sm.g.fqb[nl][c];
    float tv[8], Ar[64];
#pragma unroll
    for (int oo = 0; oo < 8; oo++) {
      float acc = 0.f;
#pragma unroll
      for (int c = 0; c < 8; c++) acc += sm.g.Dlds[obase + oo][c] * fq[c];
      tv[oo] = acc;
#pragma unroll
      for (int c = 0; c < 8; c++) Ar[oo * 8 + c] = sm.g.Alds[obase + oo][c];
    }
    float s = 0.f, s2 = 0.f;
    for (int k = 0; k < 16; k++) {
      float4 g0 = *(const float4*)&sm.g.fnb[nl][k * 8];
      float4 g1 = *(const float4*)&sm.g.fnb[nl][k * 8 + 4];
      float fn[8] = {g0.x, g0.y, g0.z, g0.w, g1.x, g1.y, g1.z, g1.w};
#pragma unroll
      for (int oo = 0; oo < 8; oo++) {
        float acc = tv[oo];
#pragma unroll
        for (int c = 0; c < 8; c++) acc += Ar[oo * 8 + c] * fn[c];
        s += acc; s2 += acc * acc;
      }
    }
#pragma unroll
    for (int m = 1; m < 64; m <<= 1) {
      s += __shfl_xor(s, m, 64);
      s2 += __shfl_xor(s2, m, 64);
    }
    if ((tid & 63) == 0) {
      int g = tid >> 6;
      atomicAdd(&stats[((b << 2) + g) * 2 + 0], (double)s);
      atomicAdd(&stats[((b << 2) + g) * 2 + 1], (double)s2);
    }
    __syncthreads();
    if (tid == 0) {
      __threadfence();
      int old = __hip_atomic_fetch_add(&ctl->stats_done, 1, __ATOMIC_ACQ_REL,
                                       __HIP_MEMORY_SCOPE_AGENT);
      sm.g.last = (old == 2047);
    }
    __syncthreads();
    if (sm.g.last) {
      if (tid < 32) {
        unsigned long long r0 = __hip_atomic_load((unsigned long long*)&stats[tid * 2],
                                                  __ATOMIC_RELAXED, __HIP_MEMORY_SCOPE_AGENT);
        unsigned long long r1 = __hip_atomic_load((unsigned long long*)&stats[tid * 2 + 1],
                                                  __ATOMIC_RELAXED, __HIP_MEMORY_SCOPE_AGENT);
        double cnt = 2097152.0;                   // 32 * 4096 * 16
        double mean = __longlong_as_double((long long)r0) / cnt;
        double var = __longlong_as_double((long long)r1) / cnt - mean * mean;
        float rstd = (float)(1.0 / sqrt(var + 1e-5));
        musd[tid * 2] = (float)mean;
        musd[tid * 2 + 1] = rstd;
      }
      __syncthreads();
      if (tid == 0) release_inc(&ctl->fin_done);
    }
  } else if (bk < 2824) {
    // ================= out1: recompute h for selected, GN+leaky+max =========
    int rel = bk - 2312;
    int b = rel >> 6;
    int j0 = (rel & 63) << 4;
    if (tid == 0) {
      spin_ge(&ctl->fps_prog[b], j0 + 15);        // only need fps prefix
      spin_ge(&ctl->fin_done, 1);
    }
    __syncthreads();
    __threadfence();
    float* out1 = out + 24576;
    if (tid < 128) {
#pragma unroll
      for (int c = 0; c < 8; c++) {
        float a = w1[tid * 16 + c];
        sm.g.Alds[tid][c] = a;
        sm.g.Dlds[tid][c] = w1[tid * 16 + 8 + c] - a;
      }
    }
    int nl = tid & 15, kk = tid >> 4;
    int nmy = fps_g[b * NPT + j0 + nl];
    int idx = knn[(((size_t)(b << 12) + nmy) << 4) + kk];
    const float4* fp4 = (const float4*)(f8t + (((size_t)(b << 12) + idx) << 3));
    float4 v0 = fp4[0], v1 = fp4[1];
    float* dstp = &sm.g.fnb[nl][kk << 3];
    ((float4*)dstp)[0] = v0;
    ((float4*)dstp)[1] = v1;
    if (tid < 16) {
      int nq = fps_g[b * NPT + j0 + tid];
      const float4* fq4 = (const float4*)(f8t + (((size_t)(b << 12) + nq) << 3));
      float4 a = fq4[0], c4 = fq4[1];
      sm.g.fqb[tid][0] = a.x; sm.g.fqb[tid][1] = a.y; sm.g.fqb[tid][2] = a.z; sm.g.fqb[tid][3] = a.w;
      sm.g.fqb[tid][4] = c4.x; sm.g.fqb[tid][5] = c4.y; sm.g.fqb[tid][6] = c4.z; sm.g.fqb[tid][7] = c4.w;
    }
    __syncthreads();
    int o8 = tid >> 4;
    int obase = o8 << 3;
    float fq[8];
#pragma unroll
    for (int c = 0; c < 8; c++) fq[c] = sm.g.fqb[nl][c];
    float tv[8], Ar[64];
#pragma unroll
    for (int oo = 0; oo < 8; oo++) {
      float acc = 0.f;
#pragma unroll
      for (int c = 0; c < 8; c++) acc += sm.g.Dlds[obase + oo][c] * fq[c];
      tv[oo] = acc;
#pragma unroll
      for (int c = 0; c < 8; c++) Ar[oo * 8 + c] = sm.g.Alds[obase + oo][c];
    }
    float mx[8], mn[8];
#pragma unroll
    for (int oo = 0; oo < 8; oo++) { mx[oo] = -3.4e38f; mn[oo] = 3.4e38f; }
    for (int k = 0; k < 16; k++) {
      float4 g0 = *(const float4*)&sm.g.fnb[nl][k * 8];
      float4 g1 = *(const float4*)&sm.g.fnb[nl][k * 8 + 4];
      float fn[8] = {g0.x, g0.y, g0.z, g0.w, g1.x, g1.y, g1.z, g1.w};
#pragma unroll
      for (int oo = 0; oo < 8; oo++) {
        float acc = tv[oo];
#pragma unroll
        for (int c = 0; c < 8; c++) acc += Ar[oo * 8 + c] * fn[c];
        mx[oo] = fmaxf(mx[oo], acc);
        mn[oo] = fminf(mn[oo], acc);
      }
    }
    int g = o8 >> 2;
    int j = j0 + nl;
    float mu = musd[((b << 2) + g) * 2];
    float rstd = musd[((b << 2) + g) * 2 + 1];
#pragma unroll
    for (int oo = 0; oo < 8; oo++) {
      int o = obase + oo;
      float w = gnw[o];
      float v = (w >= 0.f) ? mx[oo] : mn[oo];   // leaky∘affine weakly monotone
      float y = (v - mu) * rstd * w + gnb[o];
      y = (y >= 0.f) ? y : 0.2f * y;
      out1[(((size_t)b * 128 + o) << 10) + j] = y;
    }
  } else {
    // ================= gather: coor + fps_idx as float ======================
    int rel = bk - 2824;
    int t = rel * 256 + tid;                      // 8192 = B*NPT
    int b = t >> 10, j = t & 1023;
    int jmax = ((rel & 3) << 8) + 255;            // this block's max j
    if (tid == 0) spin_ge(&ctl->fps_prog[b], jmax);
    __syncthreads();
    __threadfence();
    int i = fps_g[t];
    const float* xb = x + (size_t)b * 3 * NQ;
    out[((size_t)b * 3 + 0) * NPT + j] = xb[i];
    out[((size_t)b * 3 + 1) * NPT + j] = xb[NQ + i];
    out[((size_t)b * 3 + 2) * NPT + j] = xb[2 * NQ + i];
    out[24576 + 1048576 + t] = (float)i;
  }
}

extern "C" void kernel_launch(void* const* d_in, const int* in_sizes, int n_in,
                              void* d_out, int out_size, void* d_ws, size_t ws_size,
                              hipStream_t stream) {
  const float* x    = (const float*)d_in[0];
  const float* f    = (const float*)d_in[1];
  const float* w_in = (const float*)d_in[2];
  const float* b_in = (const float*)d_in[3];
  const float* w1   = (const float*)d_in[4];
  const float* gnw  = (const float*)d_in[5];
  const float* gnb  = (const float*)d_in[6];
  float* out = (float*)d_out;

  char* ws = (char*)d_ws;
  float*  f8t   = (float*)(ws);                               // 1 MB
  int*    knn   = (int*)(ws + (1 << 20));                     // 2 MB
  int*    fps   = (int*)(ws + (3 << 20));                     // 32 KB
  double* stats = (double*)(ws + (3 << 20) + 32768);          // 512 B
  Ctl*    ctl   = (Ctl*)(ws + (3 << 20) + 32768 + 512);       // 64 B
  float*  musd  = (float*)(ws + (3 << 20) + 32768 + 512 + 64);// 256 B

  hipMemsetAsync(stats, 0, 512 + 64, stream);                 // stats + ctl
  mega_kernel<<<2856, 256, 0, stream>>>(x, f, w_in, b_in, w1, gnw, gnb,
                                        f8t, knn, fps, stats, musd, ctl, out);
}

// Round 6
// 960.927 us; speedup vs baseline: 1.1999x; 1.1999x over previous
//
#include <hip/hip_runtime.h>

#define NQ 4096
#define NPT 1024
#define CAP 16

typedef float vf2 __attribute__((ext_vector_type(2)));

struct KnnSm { float4 pts[2048]; unsigned long long qbuf[CAP * 256]; };   // 64 KB
struct FpsSm { float2 pxy[NQ]; float pz[NQ]; unsigned long long red[2][4]; };  // 48.1 KB
struct GemmSm {
  float fnb[16][132]; float fqb[16][8]; float Alds[128][8]; float Dlds[128][8];
  int last;
};
union FusedSm { KnnSm k; FpsSm f; GemmSm g; };

struct Ctl { int f8_done, knn_done, fps_done, stats_done, fin_done, pad0, pad1, pad2;
             int fps_prog[8]; };   // zeroed by memset each launch

// lexicographic max of (hi,lo) across wave via DPP; result lands in lane 63.
// bound_ctrl=true: invalid lanes read (0,0); real keys have lo>=it>=1 so (0,0)
// always loses (strict >).
#define DPP_STEP(CTRL)                                                          \
  {                                                                             \
    unsigned sh = (unsigned)__builtin_amdgcn_update_dpp(0, (int)hi, CTRL, 0xF, 0xF, true); \
    unsigned sl = (unsigned)__builtin_amdgcn_update_dpp(0, (int)lo, CTRL, 0xF, 0xF, true); \
    bool tk = (sh > hi) || ((sh == hi) && (sl > lo));                           \
    hi = tk ? sh : hi;                                                          \
    lo = tk ? sl : lo;                                                          \
  }

__device__ inline void spin_ge(int* p, int target) {
  while (__hip_atomic_load(p, __ATOMIC_RELAXED, __HIP_MEMORY_SCOPE_AGENT) < target)
    __builtin_amdgcn_s_sleep(32);
}
__device__ inline void release_inc(int* p) {
  __threadfence();
  __hip_atomic_fetch_add(p, 1, __ATOMIC_RELAXED, __HIP_MEMORY_SCOPE_AGENT);
}

__global__ __launch_bounds__(256) void mega_kernel(
    const float* __restrict__ x, const float* __restrict__ f,
    const float* __restrict__ w_in, const float* __restrict__ b_in,
    const float* __restrict__ w1, const float* __restrict__ gnw,
    const float* __restrict__ gnb, float* __restrict__ f8t,
    int* __restrict__ knn, int* __restrict__ fps_g, double* __restrict__ stats,
    float* __restrict__ musd, Ctl* __restrict__ ctl, float* __restrict__ out) {
  __shared__ FusedSm sm;
  int tid = threadIdx.x;
  int bk = blockIdx.x;

  if (bk < 8) {
    // ===== FPS: barrier-FREE iteration via tagged-LDS poll ===================
#pragma clang fp contract(off)
    int b = bk;
    const float* xb = x + (size_t)b * 3 * NQ;
    if (tid < 8) ((unsigned long long*)sm.f.red)[tid] = 0ull;  // tag 0: never matches (it>=1)
    vf2 px2[8], py2[8], pz2[8], d2[8];
#pragma unroll
    for (int p = 0; p < 8; p++) {
      int i0 = (p << 9) + tid, i1 = i0 + 256;   // slot 2p -> i0, slot 2p+1 -> i1
      float X0 = xb[i0], Y0 = xb[NQ + i0], Z0 = xb[2 * NQ + i0];
      float X1 = xb[i1], Y1 = xb[NQ + i1], Z1 = xb[2 * NQ + i1];
      px2[p] = vf2{X0, X1}; py2[p] = vf2{Y0, Y1}; pz2[p] = vf2{Z0, Z1};
      sm.f.pxy[i0] = make_float2(X0, Y0); sm.f.pz[i0] = Z0;
      sm.f.pxy[i1] = make_float2(X1, Y1); sm.f.pz[i1] = Z1;
    }
    float x0 = xb[0], y0 = xb[NQ], z0 = xb[2 * NQ];
    {
      vf2 wxv = vf2{x0, x0}, wyv = vf2{y0, y0}, wzv = vf2{z0, z0};
#pragma unroll
      for (int p = 0; p < 8; p++) {
        vf2 dx = px2[p] - wxv, dy = py2[p] - wyv, dz = pz2[p] - wzv;
        vf2 a = dx * dx, bq = dy * dy, cq = dz * dz;
        d2[p] = (a + bq) + cq;                    // ((a+b)+c), no fma
      }
    }
    if (tid == 0) fps_g[b * NPT] = 0;
    __syncthreads();                              // the ONLY barrier (init)
    for (int it = 1; it < NPT; it++) {
      // tree argmax over 16 slots; strict > keeps lower slot = lower global idx
      float tv[8]; int ts[8];
#pragma unroll
      for (int s = 0; s < 8; s++) {
        bool g = d2[s].y > d2[s].x;
        tv[s] = g ? d2[s].y : d2[s].x;
        ts[s] = g ? (2 * s + 1) : (2 * s);
      }
#pragma unroll
      for (int s = 0; s < 4; s++) {
        bool g = tv[2 * s + 1] > tv[2 * s];
        tv[s] = g ? tv[2 * s + 1] : tv[2 * s];
        ts[s] = g ? ts[2 * s + 1] : ts[2 * s];
      }
#pragma unroll
      for (int s = 0; s < 2; s++) {
        bool g = tv[2 * s + 1] > tv[2 * s];
        tv[s] = g ? tv[2 * s + 1] : tv[2 * s];
        ts[s] = g ? ts[2 * s + 1] : ts[2 * s];
      }
      bool gf = tv[1] > tv[0];
      float mv = gf ? tv[1] : tv[0];
      int ms = gf ? ts[1] : ts[0];
      // key: [dist 32][inv_idx 12][it 10]; dist>=0 => bits uint-monotone;
      // max inv_idx = lowest idx = np.argmax tie-break; it equal on all lanes
      unsigned hi = __float_as_uint(mv);
      unsigned lo = (((4095u - (unsigned)((ms << 8) + tid))) << 10) | (unsigned)it;
      DPP_STEP(0x111)  // row_shr:1
      DPP_STEP(0x112)  // row_shr:2
      DPP_STEP(0x114)  // row_shr:4
      DPP_STEP(0x118)  // row_shr:8
      DPP_STEP(0x142)  // row_bcast:15
      DPP_STEP(0x143)  // row_bcast:31  -> lane 63 holds wave max
      unsigned long long* rp = &sm.f.red[it & 1][0];
      if ((tid & 63) == 63)
        __hip_atomic_store(&rp[tid >> 6], ((unsigned long long)hi << 32) | lo,
                           __ATOMIC_RELAXED, __HIP_MEMORY_SCOPE_WORKGROUP);
      // poll the 4 tagged partials; parity double-buffer + unique tags => no ABA.
      // safe: a wave writes iter-it only after fully finishing it-1, so a
      // successful poll implies no wave still reads the other parity buffer.
      unsigned long long r0, r1, r2, r3;
      unsigned long long tgt = (unsigned long long)(unsigned)it;
      while (true) {
        r0 = __hip_atomic_load(&rp[0], __ATOMIC_RELAXED, __HIP_MEMORY_SCOPE_WORKGROUP);
        r1 = __hip_atomic_load(&rp[1], __ATOMIC_RELAXED, __HIP_MEMORY_SCOPE_WORKGROUP);
        r2 = __hip_atomic_load(&rp[2], __ATOMIC_RELAXED, __HIP_MEMORY_SCOPE_WORKGROUP);
        r3 = __hip_atomic_load(&rp[3], __ATOMIC_RELAXED, __HIP_MEMORY_SCOPE_WORKGROUP);
        if ((((r0 ^ tgt) | (r1 ^ tgt) | (r2 ^ tgt) | (r3 ^ tgt)) & 1023ull) == 0ull)
          break;
      }
      unsigned long long ka = (r1 > r0) ? r1 : r0;
      unsigned long long kb = (r3 > r2) ? r3 : r2;
      unsigned long long k = (kb > ka) ? kb : ka;
      int wi = 4095 - (int)((unsigned)(k >> 10) & 4095u);
      float2 wxy = sm.f.pxy[wi];                  // one latency window:
      float wz = sm.f.pz[wi];                     // b64 + b32 issued together
      if (tid == 0) {
        fps_g[b * NPT + it] = wi;
        if (((it + 1) & 63) == 0) {               // publish prefix progress
          __threadfence();
          __hip_atomic_store(&ctl->fps_prog[b], it, __ATOMIC_RELAXED,
                             __HIP_MEMORY_SCOPE_AGENT);
        }
      }
      vf2 wxv = vf2{wxy.x, wxy.x}, wyv = vf2{wxy.y, wxy.y}, wzv = vf2{wz, wz};
#pragma unroll
      for (int p = 0; p < 8; p++) {
        vf2 dx = px2[p] - wxv, dy = py2[p] - wyv, dz = pz2[p] - wzv;
        vf2 a = dx * dx, bq = dy * dy, cq = dz * dz;
        vf2 d = (a + bq) + cq;                    // ((a+b)+c) preserved
        d2[p].x = fminf(d2[p].x, d.x);
        d2[p].y = fminf(d2[p].y, d.y);
      }
    }
  } else if (bk < 136) {
    // ================= kNN, lazy-queue top-16 (transposed queue) =============
#pragma clang fp contract(off)
    int rel = bk - 8;
    int b = rel >> 4;
    int n0 = (rel & 15) << 8;
    const float* xb = x + (size_t)b * 3 * NQ;
    int n = n0 + tid;
    float qx = xb[n], qy = xb[NQ + n], qz = xb[2 * NQ + n];
    float qw = (qx * qx + qy * qy) + qz * qz;
    float bd[16]; int bi[16];
#pragma unroll
    for (int i = 0; i < 16; i++) { bd[i] = 3.4e38f; bi[i] = -1; }
    float thr = 3.4e38f;
    int cnt = 0;

    auto insert16 = [&](float ed, int em) {
#pragma unroll
      for (int i2 = 15; i2 >= 1; --i2) {
        bool ltp = ed < bd[i2 - 1];
        bool ltc = ed < bd[i2];
        float nv = ltp ? bd[i2 - 1] : ed;
        int ni = ltp ? bi[i2 - 1] : em;
        bd[i2] = ltc ? nv : bd[i2];
        bi[i2] = ltc ? ni : bi[i2];
      }
      bool lt0 = ed < bd[0];
      bd[0] = lt0 ? ed : bd[0];
      bi[0] = lt0 ? em : bi[0];
    };
    auto drain = [&]() {
#pragma unroll 1
      for (int j = 0; j < cnt; j++) {
        unsigned long long e = sm.k.qbuf[j * 256 + tid];
        float ed = __uint_as_float((unsigned int)(e >> 32));
        int em = (int)(e & 0xFFFFFFFFull);
        if (ed < bd[15]) insert16(ed, em);
      }
      cnt = 0;
      thr = bd[15];
    };

    for (int c0 = 0; c0 < NQ; c0 += 2048) {
      __syncthreads();
      for (int i = tid; i < 2048; i += 256) {
        int g = c0 + i;
        float pxv = xb[g], pyv = xb[NQ + g], pzv = xb[2 * NQ + g];
        float sq = (pxv * pxv + pyv * pyv) + pzv * pzv;
        sm.k.pts[i] = make_float4(pxv, pyv, pzv, sq);
      }
      __syncthreads();
      for (int m0 = 0; m0 < 2048; m0 += 8) {
        float4 p[8];
#pragma unroll
        for (int j = 0; j < 8; j++) p[j] = sm.k.pts[m0 + j];
        float d[8];
#pragma unroll
        for (int j = 0; j < 8; j++) {
          float dot = (qx * p[j].x + qy * p[j].y) + qz * p[j].z;
          d[j] = (qw + p[j].w) - 2.0f * dot;
        }
#pragma unroll
        for (int j = 0; j < 8; j++) {
          if (d[j] < thr) {
            sm.k.qbuf[cnt * 256 + tid] =
                ((unsigned long long)__float_as_uint(d[j]) << 32) |
                (unsigned int)(c0 + m0 + j);
            cnt++;
          }
        }
        if (__ballot(cnt > CAP - 8)) drain();
      }
    }
    drain();

    int4* dst = (int4*)(knn + (((size_t)(b << 12) + n) << 4));
    dst[0] = make_int4(bi[0], bi[1], bi[2], bi[3]);
    dst[1] = make_int4(bi[4], bi[5], bi[6], bi[7]);
    dst[2] = make_int4(bi[8], bi[9], bi[10], bi[11]);
    dst[3] = make_int4(bi[12], bi[13], bi[14], bi[15]);
    __syncthreads();
    if (tid == 0) release_inc(&ctl->knn_done);
  } else if (bk < 264) {
    // ================= f8 (1x1 conv) ========================================
    int rel = bk - 136;
    int t = rel * 256 + tid;
    int b = t >> 12, n = t & 4095;
    const float* fb = f + (size_t)b * 3 * NQ + n;
    float f0 = fb[0], f1 = fb[NQ], f2 = fb[2 * NQ];
    float o8v[8];
#pragma unroll
    for (int o = 0; o < 8; o++) {
      o8v[o] = w_in[o * 3 + 0] * f0 + w_in[o * 3 + 1] * f1 + w_in[o * 3 + 2] * f2 + b_in[o];
    }
    float4* dst = (float4*)(f8t + ((size_t)t << 3));
    dst[0] = make_float4(o8v[0], o8v[1], o8v[2], o8v[3]);
    dst[1] = make_float4(o8v[4], o8v[5], o8v[6], o8v[7]);
    __syncthreads();
    if (tid == 0) release_inc(&ctl->f8_done);
  } else if (bk < 2312) {
    // ================= stats (+ inline finalize in last block) ==============
    if (tid == 0) { spin_ge(&ctl->knn_done, 128); spin_ge(&ctl->f8_done, 128); }
    __syncthreads();
    __threadfence();
    int rel = bk - 264;
    int b = rel >> 8;
    int n0 = (rel & 255) << 4;
    if (tid < 128) {
#pragma unroll
      for (int c = 0; c < 8; c++) {
        float a = w1[tid * 16 + c];
        sm.g.Alds[tid][c] = a;
        sm.g.Dlds[tid][c] = w1[tid * 16 + 8 + c] - a;
      }
    }
    int nl = tid & 15, kk = tid >> 4;
    int nmy = n0 + nl;
    int idx = knn[(((size_t)(b << 12) + nmy) << 4) + kk];
    const float4* fp4 = (const float4*)(f8t + (((size_t)(b << 12) + idx) << 3));
    float4 v0 = fp4[0], v1 = fp4[1];
    float* dstp = &sm.g.fnb[nl][kk << 3];
    ((float4*)dstp)[0] = v0;
    ((float4*)dstp)[1] = v1;
    if (tid < 16) {
      const float4* fq4 = (const float4*)(f8t + (((size_t)(b << 12) + n0 + tid) << 3));
      float4 a = fq4[0], c4 = fq4[1];
      sm.g.fqb[tid][0] = a.x; sm.g.fqb[tid][1] = a.y; sm.g.fqb[tid][2] = a.z; sm.g.fqb[tid][3] = a.w;
      sm.g.fqb[tid][4] = c4.x; sm.g.fqb[tid][5] = c4.y; sm.g.fqb[tid][6] = c4.z; sm.g.fqb[tid][7] = c4.w;
    }
    __syncthreads();
    int o8 = tid >> 4;
    int obase = o8 << 3;
    float fq[8];
#pragma unroll
    for (int c = 0; c < 8; c++) fq[c] = sm.g.fqb[nl][c];
    float tv[8], Ar[64];
#pragma unroll
    for (int oo = 0; oo < 8; oo++) {
      float acc = 0.f;
#pragma unroll
      for (int c = 0; c < 8; c++) acc += sm.g.Dlds[obase + oo][c] * fq[c];
      tv[oo] = acc;
#pragma unroll
      for (int c = 0; c < 8; c++) Ar[oo * 8 + c] = sm.g.Alds[obase + oo][c];
    }
    float s = 0.f, s2 = 0.f;
    for (int k = 0; k < 16; k++) {
      float4 g0 = *(const float4*)&sm.g.fnb[nl][k * 8];
      float4 g1 = *(const float4*)&sm.g.fnb[nl][k * 8 + 4];
      float fn[8] = {g0.x, g0.y, g0.z, g0.w, g1.x, g1.y, g1.z, g1.w};
#pragma unroll
      for (int oo = 0; oo < 8; oo++) {
        float acc = tv[oo];
#pragma unroll
        for (int c = 0; c < 8; c++) acc += Ar[oo * 8 + c] * fn[c];
        s += acc; s2 += acc * acc;
      }
    }
#pragma unroll
    for (int m = 1; m < 64; m <<= 1) {
      s += __shfl_xor(s, m, 64);
      s2 += __shfl_xor(s2, m, 64);
    }
    if ((tid & 63) == 0) {
      int g = tid >> 6;
      atomicAdd(&stats[((b << 2) + g) * 2 + 0], (double)s);
      atomicAdd(&stats[((b << 2) + g) * 2 + 1], (double)s2);
    }
    __syncthreads();
    if (tid == 0) {
      __threadfence();
      int old = __hip_atomic_fetch_add(&ctl->stats_done, 1, __ATOMIC_ACQ_REL,
                                       __HIP_MEMORY_SCOPE_AGENT);
      sm.g.last = (old == 2047);
    }
    __syncthreads();
    if (sm.g.last) {
      if (tid < 32) {
        unsigned long long r0 = __hip_atomic_load((unsigned long long*)&stats[tid * 2],
                                                  __ATOMIC_RELAXED, __HIP_MEMORY_SCOPE_AGENT);
        unsigned long long r1 = __hip_atomic_load((unsigned long long*)&stats[tid * 2 + 1],
                                                  __ATOMIC_RELAXED, __HIP_MEMORY_SCOPE_AGENT);
        double cnt = 2097152.0;                   // 32 * 4096 * 16
        double mean = __longlong_as_double((long long)r0) / cnt;
        double var = __longlong_as_double((long long)r1) / cnt - mean * mean;
        float rstd = (float)(1.0 / sqrt(var + 1e-5));
        musd[tid * 2] = (float)mean;
        musd[tid * 2 + 1] = rstd;
      }
      __syncthreads();
      if (tid == 0) release_inc(&ctl->fin_done);
    }
  } else if (bk < 2824) {
    // ================= out1: recompute h for selected, GN+leaky+max =========
    int rel = bk - 2312;
    int b = rel >> 6;
    int j0 = (rel & 63) << 4;
    if (tid == 0) {
      spin_ge(&ctl->fps_prog[b], j0 + 15);        // only need fps prefix
      spin_ge(&ctl->fin_done, 1);
    }
    __syncthreads();
    __threadfence();
    float* out1 = out + 24576;
    if (tid < 128) {
#pragma unroll
      for (int c = 0; c < 8; c++) {
        float a = w1[tid * 16 + c];
        sm.g.Alds[tid][c] = a;
        sm.g.Dlds[tid][c] = w1[tid * 16 + 8 + c] - a;
      }
    }
    int nl = tid & 15, kk = tid >> 4;
    int nmy = fps_g[b * NPT + j0 + nl];
    int idx = knn[(((size_t)(b << 12) + nmy) << 4) + kk];
    const float4* fp4 = (const float4*)(f8t + (((size_t)(b << 12) + idx) << 3));
    float4 v0 = fp4[0], v1 = fp4[1];
    float* dstp = &sm.g.fnb[nl][kk << 3];
    ((float4*)dstp)[0] = v0;
    ((float4*)dstp)[1] = v1;
    if (tid < 16) {
      int nq = fps_g[b * NPT + j0 + tid];
      const float4* fq4 = (const float4*)(f8t + (((size_t)(b << 12) + nq) << 3));
      float4 a = fq4[0], c4 = fq4[1];
      sm.g.fqb[tid][0] = a.x; sm.g.fqb[tid][1] = a.y; sm.g.fqb[tid][2] = a.z; sm.g.fqb[tid][3] = a.w;
      sm.g.fqb[tid][4] = c4.x; sm.g.fqb[tid][5] = c4.y; sm.g.fqb[tid][6] = c4.z; sm.g.fqb[tid][7] = c4.w;
    }
    __syncthreads();
    int o8 = tid >> 4;
    int obase = o8 << 3;
    float fq[8];
#pragma unroll
    for (int c = 0; c < 8; c++) fq[c] = sm.g.fqb[nl][c];
    float tv[8], Ar[64];
#pragma unroll
    for (int oo = 0; oo < 8; oo++) {
      float acc = 0.f;
#pragma unroll
      for (int c = 0; c < 8; c++) acc += sm.g.Dlds[obase + oo][c] * fq[c];
      tv[oo] = acc;
#pragma unroll
      for (int c = 0; c < 8; c++) Ar[oo * 8 + c] = sm.g.Alds[obase + oo][c];
    }
    float mx[8], mn[8];
#pragma unroll
    for (int oo = 0; oo < 8; oo++) { mx[oo] = -3.4e38f; mn[oo] = 3.4e38f; }
    for (int k = 0; k < 16; k++) {
      float4 g0 = *(const float4*)&sm.g.fnb[nl][k * 8];
      float4 g1 = *(const float4*)&sm.g.fnb[nl][k * 8 + 4];
      float fn[8] = {g0.x, g0.y, g0.z, g0.w, g1.x, g1.y, g1.z, g1.w};
#pragma unroll
      for (int oo = 0; oo < 8; oo++) {
        float acc = tv[oo];
#pragma unroll
        for (int c = 0; c < 8; c++) acc += Ar[oo * 8 + c] * fn[c];
        mx[oo] = fmaxf(mx[oo], acc);
        mn[oo] = fminf(mn[oo], acc);
      }
    }
    int g = o8 >> 2;
    int j = j0 + nl;
    float mu = musd[((b << 2) + g) * 2];
    float rstd = musd[((b << 2) + g) * 2 + 1];
#pragma unroll
    for (int oo = 0; oo < 8; oo++) {
      int o = obase + oo;
      float w = gnw[o];
      float v = (w >= 0.f) ? mx[oo] : mn[oo];   // leaky∘affine weakly monotone
      float y = (v - mu) * rstd * w + gnb[o];
      y = (y >= 0.f) ? y : 0.2f * y;
      out1[(((size_t)b * 128 + o) << 10) + j] = y;
    }
  } else {
    // ================= gather: coor + fps_idx as float ======================
    int rel = bk - 2824;
    int t = rel * 256 + tid;                      // 8192 = B*NPT
    int b = t >> 10, j = t & 1023;
    int jmax = ((rel & 3) << 8) + 255;            // this block's max j
    if (tid == 0) spin_ge(&ctl->fps_prog[b], jmax);
    __syncthreads();
    __threadfence();
    int i = fps_g[t];
    const float* xb = x + (size_t)b * 3 * NQ;
    out[((size_t)b * 3 + 0) * NPT + j] = xb[i];
    out[((size_t)b * 3 + 1) * NPT + j] = xb[NQ + i];
    out[((size_t)b * 3 + 2) * NPT + j] = xb[2 * NQ + i];
    out[24576 + 1048576 + t] = (float)i;
  }
}

extern "C" void kernel_launch(void* const* d_in, const int* in_sizes, int n_in,
                              void* d_out, int out_size, void* d_ws, size_t ws_size,
                              hipStream_t stream) {
  const float* x    = (const float*)d_in[0];
  const float* f    = (const float*)d_in[1];
  const float* w_in = (const float*)d_in[2];
  const float* b_in = (const float*)d_in[3];
  const float* w1   = (const float*)d_in[4];
  const float* gnw  = (const float*)d_in[5];
  const float* gnb  = (const float*)d_in[6];
  float* out = (float*)d_out;

  char* ws = (char*)d_ws;
  float*  f8t   = (float*)(ws);                               // 1 MB
  int*    knn   = (int*)(ws + (1 << 20));                     // 2 MB
  int*    fps   = (int*)(ws + (3 << 20));                     // 32 KB
  double* stats = (double*)(ws + (3 << 20) + 32768);          // 512 B
  Ctl*    ctl   = (Ctl*)(ws + (3 << 20) + 32768 + 512);       // 64 B
  float*  musd  = (float*)(ws + (3 << 20) + 32768 + 512 + 64);// 256 B

  hipMemsetAsync(stats, 0, 512 + 64, stream);                 // stats + ctl
  mega_kernel<<<2856, 256, 0, stream>>>(x, f, w_in, b_in, w1, gnw, gnb,
                                        f8t, knn, fps, stats, musd, ctl, out);
}